// Round 7
// baseline (174.535 us; speedup 1.0000x reference)
//
#include <hip/hip_runtime.h>

#define BATCH 8
#define NN 10000      // nodes per graph (N)
#define STB 1024      // 16 waves/CU; LDS: shared acc 40K + table 40K = 80KB

typedef _Float16 h2 __attribute__((ext_vector_type(2)));

// Packed 2xf16 LDS atomic add (ds_pk_add_f16): one atomic covers TWO batches.
__device__ __forceinline__ void lds_pk_add(h2* p, h2 v) {
    __builtin_amdgcn_ds_atomic_fadd_v2f16(
        (__attribute__((address_space(3))) h2*)p, v);
}

// prep: fx2[bp*N + t] = { tanh(values[2bp*N+t]), tanh(values[(2bp+1)*N+t]) }
__global__ __launch_bounds__(256) void prep_kernel(
        const float* __restrict__ values, h2* __restrict__ fx2, int N)
{
    int i = blockIdx.x * 256 + threadIdx.x;
    if (i >= 4 * N) return;
    int bp = i / N, t = i - bp * N;
    float a = values[(long)(2 * bp) * N + t];
    float b = values[(long)(2 * bp + 1) * N + t];
    h2 f = { (_Float16)tanhf(a), (_Float16)tanhf(b) };
    fx2[i] = f;
}

// Scatter, decisive A/B probe:
//  - gather table in LDS (no divergent VMEM -- that law bound rounds 0-4)
//  - ONE shared acc copy, ALL edges via ds_pk_add_f16 (race-free atomics)
//  - 1024 threads = 16 waves/CU (R6 was latency-starved at 2 waves)
// If the "3.6 cyc/lane DS-atomic law" is real, this lands back at ~47us
// (finally isolating it). If atomics are bank-parallel like normal DS ops,
// this is ~8-18us.
__global__ __launch_bounds__(STB, 1) void scatter_kernel(
        const h2* __restrict__ g2,       // [4*N] packed gather values
        const float* __restrict__ w,     // [E]
        const int* __restrict__ idx,     // [2,E]
        h2* __restrict__ partial,
        int E, int N, int chunk, long goff, long soff)
{
    __shared__ __align__(16) char smem[80000];
    h2* acc   = (h2*)smem;                   // [NN] shared accumulator
    h2* table = (h2*)(smem + 40000);         // [NN] gather table

    const int tid = threadIdx.x;
    const int k = blockIdx.x, bp = blockIdx.y;
    const h2* __restrict__ gb = g2 + (long)bp * N;

    // zero acc (40KB) and stage gather table (40KB, L2-broadcast)
    int4* az = (int4*)smem;
    for (int i = tid; i < 2500; i += STB) az[i] = make_int4(0, 0, 0, 0);
    int4* tz = (int4*)(smem + 40000);
    const int4* gsrc = (const int4*)gb;
    for (int i = tid; i < 2500; i += STB) tz[i] = gsrc[i];
    __syncthreads();

    long e0 = (long)k * chunk, e1 = e0 + chunk;
    if (e0 > E) e0 = E;
    if (e1 > E) e1 = E;
    long n = e1 - e0;
    long nv8 = n >> 3;                     // 8-edge groups
    const int4*   g4p = (const int4*)(idx + goff + e0);
    const int4*   s4p = (const int4*)(idx + soff + e0);
    const float4* w4p = (const float4*)(w + e0);

    for (long v = tid; v < nv8; v += STB) {
        int4 giA = g4p[2 * v], giB = g4p[2 * v + 1];
        int4 siA = s4p[2 * v], siB = s4p[2 * v + 1];
        float4 wvA = w4p[2 * v], wvB = w4p[2 * v + 1];
        // 8 independent LDS table gathers
        h2 fA0 = table[giA.x], fA1 = table[giA.y];
        h2 fA2 = table[giA.z], fA3 = table[giA.w];
        h2 fB0 = table[giB.x], fB1 = table[giB.y];
        h2 fB2 = table[giB.z], fB3 = table[giB.w];
        h2 wA0 = { (_Float16)wvA.x, (_Float16)wvA.x };
        h2 wA1 = { (_Float16)wvA.y, (_Float16)wvA.y };
        h2 wA2 = { (_Float16)wvA.z, (_Float16)wvA.z };
        h2 wA3 = { (_Float16)wvA.w, (_Float16)wvA.w };
        h2 wB0 = { (_Float16)wvB.x, (_Float16)wvB.x };
        h2 wB1 = { (_Float16)wvB.y, (_Float16)wvB.y };
        h2 wB2 = { (_Float16)wvB.z, (_Float16)wvB.z };
        h2 wB3 = { (_Float16)wvB.w, (_Float16)wvB.w };
        lds_pk_add(&acc[siA.x], wA0 * fA0);
        lds_pk_add(&acc[siA.y], wA1 * fA1);
        lds_pk_add(&acc[siA.z], wA2 * fA2);
        lds_pk_add(&acc[siA.w], wA3 * fA3);
        lds_pk_add(&acc[siB.x], wB0 * fB0);
        lds_pk_add(&acc[siB.y], wB1 * fB1);
        lds_pk_add(&acc[siB.z], wB2 * fB2);
        lds_pk_add(&acc[siB.w], wB3 * fB3);
    }
    for (long e = (nv8 << 3) + tid; e < n; e += STB) {
        int gi = idx[goff + e0 + e], si = idx[soff + e0 + e];
        _Float16 wf = (_Float16)w[e0 + e];
        h2 wb = { wf, wf };
        lds_pk_add(&acc[si], wb * table[gi]);
    }
    __syncthreads();

    // write partial row
    int4* pz = (int4*)(partial + ((long)k * 4 + bp) * N);
    for (int i = tid; i < 2500; i += STB) pz[i] = az[i];
}

// ---------------- reduce 1 (flat): pred, err, err2 ----------------
__global__ __launch_bounds__(256) void reduce1_kernel(
        const h2* __restrict__ partial,
        const float* __restrict__ values,
        float* __restrict__ pred, float* __restrict__ err,
        h2* __restrict__ err2, int N, int K)
{
    int t = blockIdx.x * 256 + threadIdx.x;
    int bp = blockIdx.y;
    if (t >= N) return;
    float sx = 0.f, sy = 0.f;
    const h2* __restrict__ p = partial + (long)bp * N + t;
#pragma unroll 8
    for (int kk = 0; kk < K; ++kk) {
        h2 v = p[(long)kk * 4 * N];
        sx += (float)v.x; sy += (float)v.y;
    }
    long j0 = (long)(2 * bp) * N + t, j1 = j0 + N;
    float v0 = values[j0], v1 = values[j1];
    float e0 = v0 - sx, e1 = v1 - sy;
    pred[j0] = sx; pred[j1] = sy;
    err[j0] = e0;  err[j1] = e1;
    h2 pk = { (_Float16)e0, (_Float16)e1 };
    err2[(long)bp * N + t] = pk;
}

// ---------------- reduce 2 (flat): dx = err - (1 - tanh^2(x)) * aggr ----------------
__global__ __launch_bounds__(256) void reduce2_kernel(
        const h2* __restrict__ partial,
        const float* __restrict__ values,
        const float* __restrict__ err,
        float* __restrict__ dx, int N, int K)
{
    int t = blockIdx.x * 256 + threadIdx.x;
    int bp = blockIdx.y;
    if (t >= N) return;
    float sx = 0.f, sy = 0.f;
    const h2* __restrict__ p = partial + (long)bp * N + t;
#pragma unroll 8
    for (int kk = 0; kk < K; ++kk) {
        h2 v = p[(long)kk * 4 * N];
        sx += (float)v.x; sy += (float)v.y;
    }
    long j0 = (long)(2 * bp) * N + t, j1 = j0 + N;
    float v0 = values[j0], v1 = values[j1];
    float f0 = tanhf(v0), f1 = tanhf(v1);
    dx[j0] = err[j0] - (1.0f - f0 * f0) * sx;
    dx[j1] = err[j1] - (1.0f - f1 * f1) * sy;
}

extern "C" void kernel_launch(void* const* d_in, const int* in_sizes, int n_in,
                              void* d_out, int out_size, void* d_ws, size_t ws_size,
                              hipStream_t stream) {
    const float* values  = (const float*)d_in[0];   // [B*N]
    const float* weights = (const float*)d_in[1];   // [E]
    const int*   edge_ix = (const int*)d_in[2];     // [2, E]

    const int BN = in_sizes[0];        // 80000
    const int E  = in_sizes[1];        // 2,000,000
    const int N  = BN / BATCH;         // 10000

    float* out  = (float*)d_out;       // [3, B*N]
    float* pred = out;
    float* err  = out + BN;
    float* dx   = out + 2 * BN;

    // workspace: fx2 [4N] h2 | err2 [4N] h2 | partial [K*4][N] h2
    auto align16 = [](size_t x) { return (x + 15) & ~(size_t)15; };
    char* ws = (char*)d_ws;
    h2* fx2 = (h2*)ws;
    size_t off = align16((size_t)4 * N * sizeof(h2));
    h2* err2 = (h2*)(ws + off);
    off += align16((size_t)4 * N * sizeof(h2));
    // K=64 -> 256 scatter blocks = 1/CU, 16 waves/CU
    int K = 64;
    while (K > 16 && off + (size_t)K * 4 * N * sizeof(h2) > ws_size) K >>= 1;
    h2* partial = (h2*)(ws + off);

    int chunk = (((E + K - 1) / K) + 7) & ~7;   // multiple of 8
    int Kused = (E + chunk - 1) / chunk;

    dim3 sgrid(Kused, 4);                 // 4 batch-pairs
    dim3 rgrid((N + 255) / 256, 4);       // flat reduce: 1 thread per (node,bp)

    prep_kernel<<<(4 * N + 255) / 256, 256, 0, stream>>>(values, fx2, N);
    scatter_kernel<<<sgrid, STB, 0, stream>>>(fx2, weights, edge_ix, partial,
                                              E, N, chunk, 0L, (long)E);
    reduce1_kernel<<<rgrid, 256, 0, stream>>>(partial, values, pred, err,
                                              err2, N, Kused);
    scatter_kernel<<<sgrid, STB, 0, stream>>>(err2, weights, edge_ix, partial,
                                              E, N, chunk, (long)E, 0L);
    reduce2_kernel<<<rgrid, 256, 0, stream>>>(partial, values, err, dx,
                                              N, Kused);
}

// Round 8
// 139.877 us; speedup vs baseline: 1.2478x; 1.2478x over previous
//
#include <hip/hip_runtime.h>

#define BATCH 8
#define NN 10000      // nodes per graph (N)
#define STB 1024      // 16 waves; scatter1 LDS 120KB, scatter2 LDS 80KB

#define FPSCALE 4194304.0f          // 2^22 fixed-point scale
#define FPINV   2.384185791e-7f     // 1 / 2^22

typedef _Float16 h2 __attribute__((ext_vector_type(2)));

// Packed 2xf16 LDS atomic add (serialized unit, ~3.5 cyc/lane -- control arm).
__device__ __forceinline__ void lds_pk_add(h2* p, h2 v) {
    __builtin_amdgcn_ds_atomic_fadd_v2f16(
        (__attribute__((address_space(3))) h2*)p, v);
}

// prep: fx2[bp*N + t] = { tanh(values[2bp*N+t]), tanh(values[(2bp+1)*N+t]) }
__global__ __launch_bounds__(256) void prep_kernel(
        const float* __restrict__ values, h2* __restrict__ fx2, int N)
{
    int i = blockIdx.x * 256 + threadIdx.x;
    if (i >= 4 * N) return;
    int bp = i / N, t = i - bp * N;
    float a = values[(long)(2 * bp) * N + t];
    float b = values[(long)(2 * bp + 1) * N + t];
    h2 f = { (_Float16)tanhf(a), (_Float16)tanhf(b) };
    fx2[i] = f;
}

// ---------------- scatter pass 1: u32 fixed-point LDS atomics (PROBE ARM) ----
// acc[2][NN] int (80KB, batch-even / batch-odd planes for full bank spread)
// + table[NN] h2 (40KB) = 120KB. All edges via ds_add_u32 -- if the integer
// LDS atomic unit is bank-parallel this runs ~10us; if serialized like the
// f16-pk unit, ~90us. Fixed-point: q = rn(w * fx * 2^22); sum bound
// deg(<=~300) * 0.06 * 2^22 ~ 7.6e7 << 2^31; quantum 2.4e-7 (better than f16).
__global__ __launch_bounds__(STB, 1) void scatter_u32_kernel(
        const h2* __restrict__ g2,       // [4*N] packed gather values
        const float* __restrict__ w,     // [E]
        const int* __restrict__ idx,     // [2,E]
        int2* __restrict__ partial,      // [K*4][N] int2
        int E, int N, int chunk, long goff, long soff)
{
    __shared__ __align__(16) int acc[2 * NN];        // 80KB
    __shared__ __align__(16) h2  table[NN];          // 40KB

    const int tid = threadIdx.x;
    const int k = blockIdx.x, bp = blockIdx.y;
    const h2* __restrict__ gb = g2 + (long)bp * N;

    int4* az = (int4*)acc;
    for (int i = tid; i < 5000; i += STB) az[i] = make_int4(0, 0, 0, 0);
    int4* tz = (int4*)table;
    const int4* gsrc = (const int4*)gb;
    for (int i = tid; i < 2500; i += STB) tz[i] = gsrc[i];
    __syncthreads();

    long e0 = (long)k * chunk, e1 = e0 + chunk;
    if (e0 > E) e0 = E;
    if (e1 > E) e1 = E;
    long n = e1 - e0;
    long nv8 = n >> 3;
    const int4*   g4p = (const int4*)(idx + goff + e0);
    const int4*   s4p = (const int4*)(idx + soff + e0);
    const float4* w4p = (const float4*)(w + e0);

    for (long v = tid; v < nv8; v += STB) {
        int4 giA = g4p[2 * v], giB = g4p[2 * v + 1];
        int4 siA = s4p[2 * v], siB = s4p[2 * v + 1];
        float4 wvA = w4p[2 * v], wvB = w4p[2 * v + 1];
        int gi[8] = { giA.x, giA.y, giA.z, giA.w, giB.x, giB.y, giB.z, giB.w };
        int si[8] = { siA.x, siA.y, siA.z, siA.w, siB.x, siB.y, siB.z, siB.w };
        float wf[8] = { wvA.x, wvA.y, wvA.z, wvA.w, wvB.x, wvB.y, wvB.z, wvB.w };
        h2 f[8];
#pragma unroll
        for (int j = 0; j < 8; ++j) f[j] = table[gi[j]];
#pragma unroll
        for (int j = 0; j < 8; ++j) {
            float ws = wf[j] * FPSCALE;
            int q0 = __float2int_rn(ws * (float)f[j].x);
            int q1 = __float2int_rn(ws * (float)f[j].y);
            atomicAdd(&acc[si[j]], q0);          // ds_add_u32, plane 0
            atomicAdd(&acc[NN + si[j]], q1);     // ds_add_u32, plane 1
        }
    }
    for (long e = (nv8 << 3) + tid; e < n; e += STB) {
        int gi = idx[goff + e0 + e], si = idx[soff + e0 + e];
        float ws = w[e0 + e] * FPSCALE;
        h2 f = table[gi];
        atomicAdd(&acc[si],      __float2int_rn(ws * (float)f.x));
        atomicAdd(&acc[NN + si], __float2int_rn(ws * (float)f.y));
    }
    __syncthreads();

    int2* pz = partial + ((long)k * 4 + bp) * N;
    for (int i = tid; i < N; i += STB) pz[i] = make_int2(acc[i], acc[NN + i]);
}

// ---------------- scatter pass 2: pk-f16 atomics (CONTROL ARM, R7 = 47.4us) --
__global__ __launch_bounds__(STB, 1) void scatter_pk_kernel(
        const h2* __restrict__ g2,
        const float* __restrict__ w,
        const int* __restrict__ idx,
        h2* __restrict__ partial,
        int E, int N, int chunk, long goff, long soff)
{
    __shared__ __align__(16) char smem[80000];
    h2* acc   = (h2*)smem;                   // [NN]
    h2* table = (h2*)(smem + 40000);         // [NN]

    const int tid = threadIdx.x;
    const int k = blockIdx.x, bp = blockIdx.y;
    const h2* __restrict__ gb = g2 + (long)bp * N;

    int4* az = (int4*)smem;
    for (int i = tid; i < 2500; i += STB) az[i] = make_int4(0, 0, 0, 0);
    int4* tz = (int4*)(smem + 40000);
    const int4* gsrc = (const int4*)gb;
    for (int i = tid; i < 2500; i += STB) tz[i] = gsrc[i];
    __syncthreads();

    long e0 = (long)k * chunk, e1 = e0 + chunk;
    if (e0 > E) e0 = E;
    if (e1 > E) e1 = E;
    long n = e1 - e0;
    long nv8 = n >> 3;
    const int4*   g4p = (const int4*)(idx + goff + e0);
    const int4*   s4p = (const int4*)(idx + soff + e0);
    const float4* w4p = (const float4*)(w + e0);

    for (long v = tid; v < nv8; v += STB) {
        int4 giA = g4p[2 * v], giB = g4p[2 * v + 1];
        int4 siA = s4p[2 * v], siB = s4p[2 * v + 1];
        float4 wvA = w4p[2 * v], wvB = w4p[2 * v + 1];
        h2 fA0 = table[giA.x], fA1 = table[giA.y];
        h2 fA2 = table[giA.z], fA3 = table[giA.w];
        h2 fB0 = table[giB.x], fB1 = table[giB.y];
        h2 fB2 = table[giB.z], fB3 = table[giB.w];
        h2 wA0 = { (_Float16)wvA.x, (_Float16)wvA.x };
        h2 wA1 = { (_Float16)wvA.y, (_Float16)wvA.y };
        h2 wA2 = { (_Float16)wvA.z, (_Float16)wvA.z };
        h2 wA3 = { (_Float16)wvA.w, (_Float16)wvA.w };
        h2 wB0 = { (_Float16)wvB.x, (_Float16)wvB.x };
        h2 wB1 = { (_Float16)wvB.y, (_Float16)wvB.y };
        h2 wB2 = { (_Float16)wvB.z, (_Float16)wvB.z };
        h2 wB3 = { (_Float16)wvB.w, (_Float16)wvB.w };
        lds_pk_add(&acc[siA.x], wA0 * fA0);
        lds_pk_add(&acc[siA.y], wA1 * fA1);
        lds_pk_add(&acc[siA.z], wA2 * fA2);
        lds_pk_add(&acc[siA.w], wA3 * fA3);
        lds_pk_add(&acc[siB.x], wB0 * fB0);
        lds_pk_add(&acc[siB.y], wB1 * fB1);
        lds_pk_add(&acc[siB.z], wB2 * fB2);
        lds_pk_add(&acc[siB.w], wB3 * fB3);
    }
    for (long e = (nv8 << 3) + tid; e < n; e += STB) {
        int gi = idx[goff + e0 + e], si = idx[soff + e0 + e];
        _Float16 wf = (_Float16)w[e0 + e];
        h2 wb = { wf, wf };
        lds_pk_add(&acc[si], wb * table[gi]);
    }
    __syncthreads();

    int4* pz = (int4*)(partial + ((long)k * 4 + bp) * N);
    for (int i = tid; i < 2500; i += STB) pz[i] = az[i];
}

// ---------------- reduce 1 (flat, int2 partials): pred, err, err2 ----------
__global__ __launch_bounds__(256) void reduce1_kernel(
        const int2* __restrict__ partial,
        const float* __restrict__ values,
        float* __restrict__ pred, float* __restrict__ err,
        h2* __restrict__ err2, int N, int K)
{
    int t = blockIdx.x * 256 + threadIdx.x;
    int bp = blockIdx.y;
    if (t >= N) return;
    int sx = 0, sy = 0;
    const int2* __restrict__ p = partial + (long)bp * N + t;
#pragma unroll 8
    for (int kk = 0; kk < K; ++kk) {
        int2 v = p[(long)kk * 4 * N];
        sx += v.x; sy += v.y;
    }
    long j0 = (long)(2 * bp) * N + t, j1 = j0 + N;
    float px = (float)sx * FPINV, py = (float)sy * FPINV;
    float v0 = values[j0], v1 = values[j1];
    float e0 = v0 - px, e1 = v1 - py;
    pred[j0] = px; pred[j1] = py;
    err[j0] = e0;  err[j1] = e1;
    h2 pk = { (_Float16)e0, (_Float16)e1 };
    err2[(long)bp * N + t] = pk;
}

// ---------------- reduce 2 (flat, h2 partials): dx ----------------
__global__ __launch_bounds__(256) void reduce2_kernel(
        const h2* __restrict__ partial,
        const float* __restrict__ values,
        const float* __restrict__ err,
        float* __restrict__ dx, int N, int K)
{
    int t = blockIdx.x * 256 + threadIdx.x;
    int bp = blockIdx.y;
    if (t >= N) return;
    float sx = 0.f, sy = 0.f;
    const h2* __restrict__ p = partial + (long)bp * N + t;
#pragma unroll 8
    for (int kk = 0; kk < K; ++kk) {
        h2 v = p[(long)kk * 4 * N];
        sx += (float)v.x; sy += (float)v.y;
    }
    long j0 = (long)(2 * bp) * N + t, j1 = j0 + N;
    float v0 = values[j0], v1 = values[j1];
    float f0 = tanhf(v0), f1 = tanhf(v1);
    dx[j0] = err[j0] - (1.0f - f0 * f0) * sx;
    dx[j1] = err[j1] - (1.0f - f1 * f1) * sy;
}

extern "C" void kernel_launch(void* const* d_in, const int* in_sizes, int n_in,
                              void* d_out, int out_size, void* d_ws, size_t ws_size,
                              hipStream_t stream) {
    const float* values  = (const float*)d_in[0];   // [B*N]
    const float* weights = (const float*)d_in[1];   // [E]
    const int*   edge_ix = (const int*)d_in[2];     // [2, E]

    const int BN = in_sizes[0];        // 80000
    const int E  = in_sizes[1];        // 2,000,000
    const int N  = BN / BATCH;         // 10000

    float* out  = (float*)d_out;       // [3, B*N]
    float* pred = out;
    float* err  = out + BN;
    float* dx   = out + 2 * BN;

    // workspace: fx2 [4N] h2 | err2 [4N] h2 | partial (int2 pass1 / h2 pass2,
    // shared buffer -- pass1 partials consumed by reduce1 before pass2 writes)
    auto align16 = [](size_t x) { return (x + 15) & ~(size_t)15; };
    char* ws = (char*)d_ws;
    h2* fx2 = (h2*)ws;
    size_t off = align16((size_t)4 * N * sizeof(h2));
    h2* err2 = (h2*)(ws + off);
    off += align16((size_t)4 * N * sizeof(h2));
    int K = 64;
    while (K > 16 && off + (size_t)K * 4 * N * sizeof(int2) > ws_size) K >>= 1;
    int2* partial_i = (int2*)(ws + off);
    h2*   partial_h = (h2*)(ws + off);

    int chunk = (((E + K - 1) / K) + 7) & ~7;   // multiple of 8
    int Kused = (E + chunk - 1) / chunk;

    dim3 sgrid(Kused, 4);                 // 4 batch-pairs
    dim3 rgrid((N + 255) / 256, 4);       // flat reduce: 1 thread per (node,bp)

    prep_kernel<<<(4 * N + 255) / 256, 256, 0, stream>>>(values, fx2, N);
    scatter_u32_kernel<<<sgrid, STB, 0, stream>>>(fx2, weights, edge_ix,
                                                  partial_i, E, N, chunk,
                                                  0L, (long)E);
    reduce1_kernel<<<rgrid, 256, 0, stream>>>(partial_i, values, pred, err,
                                              err2, N, Kused);
    scatter_pk_kernel<<<sgrid, STB, 0, stream>>>(err2, weights, edge_ix,
                                                 partial_h, E, N, chunk,
                                                 (long)E, 0L);
    reduce2_kernel<<<rgrid, 256, 0, stream>>>(partial_h, values, err, dx,
                                              N, Kused);
}

// Round 9
// 104.192 us; speedup vs baseline: 1.6751x; 1.3425x over previous
//
#include <hip/hip_runtime.h>

#define BATCH 8
#define NN 10000      // nodes per graph (N)
#define STB 1024      // 16 waves/CU; LDS: acc 80KB + table 40KB = 120KB

#define FPSCALE 4194304.0f          // 2^22 fixed-point scale
#define FPINV   2.384185791e-7f     // 1 / 2^22

typedef _Float16 h2 __attribute__((ext_vector_type(2)));

// prep: fx2[bp*N + t] = { tanh(values[2bp*N+t]), tanh(values[(2bp+1)*N+t]) }
__global__ __launch_bounds__(256) void prep_kernel(
        const float* __restrict__ values, h2* __restrict__ fx2, int N)
{
    int i = blockIdx.x * 256 + threadIdx.x;
    if (i >= 4 * N) return;
    int bp = i / N, t = i - bp * N;
    float a = values[(long)(2 * bp) * N + t];
    float b = values[(long)(2 * bp + 1) * N + t];
    h2 f = { (_Float16)tanhf(a), (_Float16)tanhf(b) };
    fx2[i] = f;
}

// Scatter via u32 fixed-point LDS atomics (bank-parallel path, isolated R8):
//  - gather table in LDS (no divergent VMEM)
//  - acc[2][NN] int planes; q = rn(w * f * 2^22); ds_add_u32 ~18cyc/wave-op
//    (E[max bank load] law) vs the serialized pk-f16 unit's 222cyc/wave-op.
//  - range: |term| < 1.5M, degree <= ~350 -> |sum| < 0.5G << 2^31.
//  - epilogue converts exact int sums -> h2 partials (f16 rounding only at
//    partial granularity, strictly better than the old all-f16 chain).
__global__ __launch_bounds__(STB, 1) void scatter_kernel(
        const h2* __restrict__ g2,       // [4*N] packed gather values
        const float* __restrict__ w,     // [E]
        const int* __restrict__ idx,     // [2,E]
        h2* __restrict__ partial,        // [K*4][N] h2
        int E, int N, int chunk, long goff, long soff)
{
    __shared__ __align__(16) int acc[2 * NN];        // 80KB
    __shared__ __align__(16) h2  table[NN];          // 40KB

    const int tid = threadIdx.x;
    const int k = blockIdx.x, bp = blockIdx.y;
    const h2* __restrict__ gb = g2 + (long)bp * N;

    int4* az = (int4*)acc;
    for (int i = tid; i < 5000; i += STB) az[i] = make_int4(0, 0, 0, 0);
    int4* tz = (int4*)table;
    const int4* gsrc = (const int4*)gb;
    for (int i = tid; i < 2500; i += STB) tz[i] = gsrc[i];
    __syncthreads();

    long e0 = (long)k * chunk, e1 = e0 + chunk;
    if (e0 > E) e0 = E;
    if (e1 > E) e1 = E;
    long n = e1 - e0;
    long nv8 = n >> 3;                     // 8-edge groups
    const int4*   g4p = (const int4*)(idx + goff + e0);
    const int4*   s4p = (const int4*)(idx + soff + e0);
    const float4* w4p = (const float4*)(w + e0);

    for (long v = tid; v < nv8; v += STB) {
        int4 giA = g4p[2 * v], giB = g4p[2 * v + 1];
        int4 siA = s4p[2 * v], siB = s4p[2 * v + 1];
        float4 wvA = w4p[2 * v], wvB = w4p[2 * v + 1];
        int gi[8] = { giA.x, giA.y, giA.z, giA.w, giB.x, giB.y, giB.z, giB.w };
        int si[8] = { siA.x, siA.y, siA.z, siA.w, siB.x, siB.y, siB.z, siB.w };
        float wf[8] = { wvA.x, wvA.y, wvA.z, wvA.w, wvB.x, wvB.y, wvB.z, wvB.w };
        h2 f[8];
#pragma unroll
        for (int j = 0; j < 8; ++j) f[j] = table[gi[j]];   // 8 independent gathers
#pragma unroll
        for (int j = 0; j < 8; ++j) {
            float ws = wf[j] * FPSCALE;
            int q0 = __float2int_rn(ws * (float)f[j].x);
            int q1 = __float2int_rn(ws * (float)f[j].y);
            atomicAdd(&acc[si[j]], q0);          // ds_add_u32, plane 0
            atomicAdd(&acc[NN + si[j]], q1);     // ds_add_u32, plane 1
        }
    }
    for (long e = (nv8 << 3) + tid; e < n; e += STB) {
        int gi = idx[goff + e0 + e], si = idx[soff + e0 + e];
        float ws = w[e0 + e] * FPSCALE;
        h2 f = table[gi];
        atomicAdd(&acc[si],      __float2int_rn(ws * (float)f.x));
        atomicAdd(&acc[NN + si], __float2int_rn(ws * (float)f.y));
    }
    __syncthreads();

    // exact int sums -> h2 partial row
    h2* pz = partial + ((long)k * 4 + bp) * N;
    for (int i = tid; i < N; i += STB) {
        h2 p = { (_Float16)((float)acc[i] * FPINV),
                 (_Float16)((float)acc[NN + i] * FPINV) };
        pz[i] = p;
    }
}

// ---------------- reduce 1 (flat): pred, err, err2 ----------------
__global__ __launch_bounds__(256) void reduce1_kernel(
        const h2* __restrict__ partial,
        const float* __restrict__ values,
        float* __restrict__ pred, float* __restrict__ err,
        h2* __restrict__ err2, int N, int K)
{
    int t = blockIdx.x * 256 + threadIdx.x;
    int bp = blockIdx.y;
    if (t >= N) return;
    float sx = 0.f, sy = 0.f;
    const h2* __restrict__ p = partial + (long)bp * N + t;
#pragma unroll 8
    for (int kk = 0; kk < K; ++kk) {
        h2 v = p[(long)kk * 4 * N];
        sx += (float)v.x; sy += (float)v.y;
    }
    long j0 = (long)(2 * bp) * N + t, j1 = j0 + N;
    float v0 = values[j0], v1 = values[j1];
    float e0 = v0 - sx, e1 = v1 - sy;
    pred[j0] = sx; pred[j1] = sy;
    err[j0] = e0;  err[j1] = e1;
    h2 pk = { (_Float16)e0, (_Float16)e1 };
    err2[(long)bp * N + t] = pk;
}

// ---------------- reduce 2 (flat): dx = err - (1 - tanh^2(x)) * aggr --------
__global__ __launch_bounds__(256) void reduce2_kernel(
        const h2* __restrict__ partial,
        const float* __restrict__ values,
        const float* __restrict__ err,
        float* __restrict__ dx, int N, int K)
{
    int t = blockIdx.x * 256 + threadIdx.x;
    int bp = blockIdx.y;
    if (t >= N) return;
    float sx = 0.f, sy = 0.f;
    const h2* __restrict__ p = partial + (long)bp * N + t;
#pragma unroll 8
    for (int kk = 0; kk < K; ++kk) {
        h2 v = p[(long)kk * 4 * N];
        sx += (float)v.x; sy += (float)v.y;
    }
    long j0 = (long)(2 * bp) * N + t, j1 = j0 + N;
    float v0 = values[j0], v1 = values[j1];
    float f0 = tanhf(v0), f1 = tanhf(v1);
    dx[j0] = err[j0] - (1.0f - f0 * f0) * sx;
    dx[j1] = err[j1] - (1.0f - f1 * f1) * sy;
}

extern "C" void kernel_launch(void* const* d_in, const int* in_sizes, int n_in,
                              void* d_out, int out_size, void* d_ws, size_t ws_size,
                              hipStream_t stream) {
    const float* values  = (const float*)d_in[0];   // [B*N]
    const float* weights = (const float*)d_in[1];   // [E]
    const int*   edge_ix = (const int*)d_in[2];     // [2, E]

    const int BN = in_sizes[0];        // 80000
    const int E  = in_sizes[1];        // 2,000,000
    const int N  = BN / BATCH;         // 10000

    float* out  = (float*)d_out;       // [3, B*N]
    float* pred = out;
    float* err  = out + BN;
    float* dx   = out + 2 * BN;

    // workspace: fx2 [4N] h2 | err2 [4N] h2 | partial [K*4][N] h2 (10.25MB)
    auto align16 = [](size_t x) { return (x + 15) & ~(size_t)15; };
    char* ws = (char*)d_ws;
    h2* fx2 = (h2*)ws;
    size_t off = align16((size_t)4 * N * sizeof(h2));
    h2* err2 = (h2*)(ws + off);
    off += align16((size_t)4 * N * sizeof(h2));
    int K = 64;                        // 256 scatter blocks = 1/CU
    while (K > 16 && off + (size_t)K * 4 * N * sizeof(h2) > ws_size) K >>= 1;
    h2* partial = (h2*)(ws + off);

    int chunk = (((E + K - 1) / K) + 7) & ~7;   // multiple of 8
    int Kused = (E + chunk - 1) / chunk;

    dim3 sgrid(Kused, 4);                 // 4 batch-pairs
    dim3 rgrid((N + 255) / 256, 4);       // flat reduce: 1 thread per (node,bp)

    prep_kernel<<<(4 * N + 255) / 256, 256, 0, stream>>>(values, fx2, N);
    // pass 1: gather src (goff=0), scatter to tgt (soff=E)
    scatter_kernel<<<sgrid, STB, 0, stream>>>(fx2, weights, edge_ix, partial,
                                              E, N, chunk, 0L, (long)E);
    reduce1_kernel<<<rgrid, 256, 0, stream>>>(partial, values, pred, err,
                                              err2, N, Kused);
    // pass 2: gather tgt (goff=E), scatter to src (soff=0)
    scatter_kernel<<<sgrid, STB, 0, stream>>>(err2, weights, edge_ix, partial,
                                              E, N, chunk, (long)E, 0L);
    reduce2_kernel<<<rgrid, 256, 0, stream>>>(partial, values, err, dx,
                                              N, Kused);
}